// Round 2
// baseline (174.914 us; speedup 1.0000x reference)
//
#include <hip/hip_runtime.h>

// Retrace loss: T=8192, K=2048, gamma=0.99.
// decay = cumprod(gamma*iw); S = reverse-cumsum(td*decay);
// retrace = S / max(decay,1e-10); loss = mean(smooth_l1(q, retrace)).
//
// Chunked scan, 3 kernels:
//  kA   : per (chunk,col) local cumprod P and local sum Zl = sum td*ld;
//         also stores y=td*ld and ld as bf16 so kB never re-reads inputs.
//  kScan: per col, exclusive chunk prefix product D0 (fwd) and suffix
//         recursion W_c = P_c*(Z_{c+1}+W_{c+1}) (bwd).  S = D0*(slocal+W).
//  kB   : backward within chunk from bf16 y/ld, fused smooth-L1 + reduce.
// All streaming kernels: float4 per thread + unroll-4 for MLP (round-1 K1
// was latency-bound at 1.4 TB/s with VGPR=8).

#define GAMMA 0.99f

constexpr int T_ = 8192;
constexpr int K_ = 2048;
constexpr int N_ = T_ - 1;                  // 8191
constexpr int L_ = 32;                      // rows per chunk
constexpr int NCHUNK = (N_ + L_ - 1) / L_;  // 256 (last chunk: 31 rows)
constexpr long long NK = (long long)N_ * K_;
constexpr int CK = NCHUNK * K_;

typedef float f4 __attribute__((ext_vector_type(4)));
typedef unsigned short us4 __attribute__((ext_vector_type(4)));

__device__ __forceinline__ unsigned short f2bf(float f) {  // RTNE
  unsigned u = __float_as_uint(f);
  u += 0x7FFFu + ((u >> 16) & 1u);
  return (unsigned short)(u >> 16);
}
__device__ __forceinline__ float bf2f(unsigned short h) {
  return __uint_as_float(((unsigned)h) << 16);
}

// ---------------------------------------------------------------- kA
template <bool STORE>
__global__ __launch_bounds__(256) void kA(
    const float* __restrict__ tsv, const float* __restrict__ tev,
    const float* __restrict__ r, const float* __restrict__ ologp,
    const float* __restrict__ tlogp, unsigned short* __restrict__ yh,
    unsigned short* __restrict__ ldh, float* __restrict__ P,
    float* __restrict__ Zl, double* __restrict__ acc) {
  const int kc = blockIdx.x * 256 + threadIdx.x;  // 0..511
  const int k = kc * 4;
  const int chunk = blockIdx.y;
  const int i0 = chunk * L_;
  const int nrow = min(L_, N_ - i0);

  f4 p = 1.f, zl = 0.f;
  auto body = [&](int s) {
    const int i = i0 + s;
    const size_t b1 = (size_t)(i + 1) * K_ + k;
    const size_t b0 = (size_t)i * K_ + k;
    f4 lw = *(const f4*)(tlogp + b1);
    f4 a = *(const f4*)(tsv + b1);
    f4 v = *(const f4*)(tev + b1);
    f4 rr = *(const f4*)(r + b0);
    const float o = ologp[i + 1];
    f4 iw, td;
#pragma unroll
    for (int j = 0; j < 4; ++j) iw[j] = __expf(fminf(lw[j] - o, 0.f));
    p *= GAMMA * iw;
#pragma unroll
    for (int j = 0; j < 4; ++j)
      td[j] = fmaf(GAMMA, fmaf(-iw[j], a[j], v[j]), rr[j]);
    f4 y = td * p;
    zl += y;
    if (STORE) {
      us4 yo, lo;
#pragma unroll
      for (int j = 0; j < 4; ++j) {
        yo[j] = f2bf(y[j]);
        lo[j] = f2bf(p[j]);
      }
      *(us4*)(yh + b0) = yo;
      *(us4*)(ldh + b0) = lo;
    }
  };

  if (nrow == L_) {
#pragma unroll 4
    for (int s = 0; s < L_; ++s) body(s);
  } else {
    for (int s = 0; s < nrow; ++s) body(s);
  }
  *(f4*)(P + (size_t)chunk * K_ + k) = p;
  *(f4*)(Zl + (size_t)chunk * K_ + k) = zl;
  if (blockIdx.x == 0 && blockIdx.y == 0 && threadIdx.x == 0) *acc = 0.0;
}

// ---------------------------------------------------------------- kScan
// Per column: D0_c = prod_{j<c} P_j (exclusive), W_c = P_c*(Z_{c+1}+W_{c+1}).
__global__ __launch_bounds__(256) void kScan(const float* __restrict__ P,
                                             const float* __restrict__ Zl,
                                             float* __restrict__ D0,
                                             float* __restrict__ W) {
  const int k = blockIdx.x * 256 + threadIdx.x;  // 0..2047
  float d = 1.f;
#pragma unroll 16
  for (int c = 0; c < NCHUNK; ++c) {
    D0[(size_t)c * K_ + k] = d;
    d *= P[(size_t)c * K_ + k];
  }
  float w = 0.f;
  W[(size_t)(NCHUNK - 1) * K_ + k] = 0.f;
#pragma unroll 16
  for (int c = NCHUNK - 2; c >= 0; --c) {
    w = P[(size_t)c * K_ + k] * (Zl[(size_t)(c + 1) * K_ + k] + w);
    W[(size_t)c * K_ + k] = w;
  }
}

// ---------------------------------------------------------------- kB
__global__ __launch_bounds__(256) void kB(
    const float* __restrict__ sv, const unsigned short* __restrict__ yh,
    const unsigned short* __restrict__ ldh, const float* __restrict__ D0,
    const float* __restrict__ W, double* __restrict__ acc) {
  const int kc = blockIdx.x * 256 + threadIdx.x;
  const int k = kc * 4;
  const int chunk = blockIdx.y;
  const int i0 = chunk * L_;
  const int nrow = min(L_, N_ - i0);

  f4 d0 = *(const f4*)(D0 + (size_t)chunk * K_ + k);
  f4 slocal = *(const f4*)(W + (size_t)chunk * K_ + k);  // start at W_c
  f4 loss = 0.f;

  auto body = [&](int s) {
    const int i = i0 + s;
    const size_t b0 = (size_t)i * K_ + k;
    us4 y4 = *(const us4*)(yh + b0);
    us4 l4 = *(const us4*)(ldh + b0);
    f4 sv4 = *(const f4*)(sv + b0);
#pragma unroll
    for (int j = 0; j < 4; ++j) {
      float y = bf2f(y4[j]);
      float ld = bf2f(l4[j]);
      slocal[j] += y;
      float S = d0[j] * slocal[j];
      float decay = d0[j] * ld;
      float retrace = S / fmaxf(decay, 1e-10f);
      float dd = sv4[j] - retrace;
      float ad = fabsf(dd);
      loss[j] += (ad < 1.f) ? 0.5f * dd * dd : ad - 0.5f;
    }
  };

  if (nrow == L_) {
#pragma unroll 4
    for (int s = L_ - 1; s >= 0; --s) body(s);
  } else {
    for (int s = nrow - 1; s >= 0; --s) body(s);
  }

  float l = loss[0] + loss[1] + loss[2] + loss[3];
  for (int off = 32; off > 0; off >>= 1) l += __shfl_down(l, off);
  __shared__ float wsum[4];
  const int lane = threadIdx.x & 63, wid = threadIdx.x >> 6;
  if (lane == 0) wsum[wid] = l;
  __syncthreads();
  if (threadIdx.x == 0)
    atomicAdd(acc, (double)(wsum[0] + wsum[1] + wsum[2] + wsum[3]));
}

// ---------------------------------------------------------------- k3f
// Fallback apply-kernel (scalar, recomputes inputs) if ws is too small.
__global__ __launch_bounds__(256) void k3f(
    const float* __restrict__ sv, const float* __restrict__ tsv,
    const float* __restrict__ tev, const float* __restrict__ r,
    const float* __restrict__ ologp, const float* __restrict__ tlogp,
    const float* __restrict__ D0, const float* __restrict__ W,
    double* __restrict__ acc) {
  const int k = blockIdx.x * 256 + threadIdx.x;
  const int chunk = blockIdx.y;
  const int i0 = chunk * L_;
  const int nrow = min(L_, N_ - i0);

  float ld[L_], td[L_];
  float p = 1.f;
#pragma unroll
  for (int s = 0; s < L_; ++s) {
    if (s < nrow) {
      const int i = i0 + s;
      const size_t base = (size_t)(i + 1) * K_ + k;
      float iw = __expf(fminf(tlogp[base] - ologp[i + 1], 0.f));
      p *= GAMMA * iw;
      ld[s] = p;
      td[s] = fmaf(GAMMA, fmaf(-iw, tsv[base], tev[base]),
                   r[(size_t)i * K_ + k]);
    }
  }
  const float d0 = D0[(size_t)chunk * K_ + k];
  float slocal = W[(size_t)chunk * K_ + k];
  float loss = 0.f;
#pragma unroll
  for (int s = L_ - 1; s >= 0; --s) {
    if (s < nrow) {
      const int i = i0 + s;
      slocal = fmaf(td[s], ld[s], slocal);
      float S = d0 * slocal;
      float retrace = S / fmaxf(d0 * ld[s], 1e-10f);
      float dd = sv[(size_t)i * K_ + k] - retrace;
      float ad = fabsf(dd);
      loss += (ad < 1.f) ? 0.5f * dd * dd : ad - 0.5f;
    }
  }
  for (int off = 32; off > 0; off >>= 1) loss += __shfl_down(loss, off);
  __shared__ float wsum[4];
  const int lane = threadIdx.x & 63, wid = threadIdx.x >> 6;
  if (lane == 0) wsum[wid] = loss;
  __syncthreads();
  if (threadIdx.x == 0)
    atomicAdd(acc, (double)(wsum[0] + wsum[1] + wsum[2] + wsum[3]));
}

// ---------------------------------------------------------------- k4
__global__ void k4(const double* __restrict__ acc, float* __restrict__ out) {
  out[0] = (float)(*acc * (1.0 / ((double)N_ * (double)K_)));
}

extern "C" void kernel_launch(void* const* d_in, const int* in_sizes, int n_in,
                              void* d_out, int out_size, void* d_ws,
                              size_t ws_size, hipStream_t stream) {
  const float* sv = (const float*)d_in[0];
  const float* tsv = (const float*)d_in[1];
  const float* tev = (const float*)d_in[2];
  const float* r = (const float*)d_in[3];
  const float* ologp = (const float*)d_in[4];
  const float* tlogp = (const float*)d_in[5];

  const size_t bfBytes = (size_t)NK * sizeof(unsigned short);  // 33.5 MB each
  const size_t scanBytes = (size_t)4 * CK * sizeof(float);     // 8 MB
  const size_t needBig = 2 * bfBytes + scanBytes + sizeof(double);

  dim3 gridV(K_ / (4 * 256), NCHUNK);  // (2, 256) for float4 kernels

  if (ws_size >= needBig) {
    unsigned short* yh = (unsigned short*)d_ws;
    unsigned short* ldh = yh + NK;
    float* f = (float*)((char*)d_ws + 2 * bfBytes);
    float* P = f;
    float* Zl = f + CK;
    float* D0 = f + 2 * (size_t)CK;
    float* W = f + 3 * (size_t)CK;
    double* acc = (double*)((char*)d_ws + 2 * bfBytes + scanBytes);

    kA<true><<<gridV, 256, 0, stream>>>(tsv, tev, r, ologp, tlogp, yh, ldh, P,
                                        Zl, acc);
    kScan<<<K_ / 256, 256, 0, stream>>>(P, Zl, D0, W);
    kB<<<gridV, 256, 0, stream>>>(sv, yh, ldh, D0, W, acc);
    k4<<<1, 1, 0, stream>>>(acc, (float*)d_out);
  } else {
    float* f = (float*)d_ws;
    float* P = f;
    float* Zl = f + CK;
    float* D0 = f + 2 * (size_t)CK;
    float* W = f + 3 * (size_t)CK;
    double* acc = (double*)(f + 4 * (size_t)CK);

    kA<false><<<gridV, 256, 0, stream>>>(tsv, tev, r, ologp, tlogp, nullptr,
                                         nullptr, P, Zl, acc);
    kScan<<<K_ / 256, 256, 0, stream>>>(P, Zl, D0, W);
    k3f<<<dim3(K_ / 256, NCHUNK), 256, 0, stream>>>(sv, tsv, tev, r, ologp,
                                                    tlogp, D0, W, acc);
    k4<<<1, 1, 0, stream>>>(acc, (float*)d_out);
  }
}

// Round 3
// 118.104 us; speedup vs baseline: 1.4810x; 1.4810x over previous
//
#include <hip/hip_runtime.h>

// Retrace loss: T=8192, K=2048, gamma=0.99.
// decay = cumprod(gamma*iw); S = reverse-cumsum(td*decay);
// retrace = S / max(decay,1e-10); loss = mean(smooth_l1(q, retrace)).
//
// Chunked scan (L=32 rows/chunk, 256 chunks), float2 per thread:
//  kA  : per (chunk,2cols) local cumprod P, local sum Zl = sum td*ld;
//        stores packed (bf16(y)<<16 | bf16(ld)) so kB never re-reads inputs.
//  kS1 : per-superchunk (16 chunks) products SP and prefixed sums SZ.
//  kS2 : per column, serial scan over 16 superchunks -> SD0, SSuf.
//  kS3 : expand to per-chunk D0 (over P, in place) and Ssuf (over Zl).
//  kB  : backward within chunk from packed y/ld; fused smooth-L1 + reduce.
// Round-2 lesson: float4 dropped occupancy to 21% (latency-bound, 2 TB/s).
// float2 restores 50% occupancy; explicit 4-row load batching forces MLP.

#define GAMMA 0.99f

constexpr int T_ = 8192;
constexpr int K_ = 2048;
constexpr int N_ = T_ - 1;        // 8191
constexpr int L_ = 32;            // rows per chunk
constexpr int NCHUNK = 256;       // (last chunk: 31 rows)
constexpr int SL = 16;            // chunks per superchunk
constexpr int SUP = NCHUNK / SL;  // 16
constexpr long long NK = (long long)N_ * K_;
constexpr int CK = NCHUNK * K_;

typedef float f2 __attribute__((ext_vector_type(2)));
typedef unsigned uu2 __attribute__((ext_vector_type(2)));

__device__ __forceinline__ unsigned short f2bf(float f) {  // RTNE
  unsigned u = __float_as_uint(f);
  u += 0x7FFFu + ((u >> 16) & 1u);
  return (unsigned short)(u >> 16);
}
__device__ __forceinline__ float bfhi(unsigned q) {  // y in hi16
  return __uint_as_float(q & 0xFFFF0000u);
}
__device__ __forceinline__ float bflo(unsigned q) {  // ld in lo16
  return __uint_as_float(q << 16);
}

// ---------------------------------------------------------------- kA
template <bool STORE>
__global__ __launch_bounds__(256) void kA(
    const float* __restrict__ tsv, const float* __restrict__ tev,
    const float* __restrict__ r, const float* __restrict__ ologp,
    const float* __restrict__ tlogp, unsigned* __restrict__ pk,
    float* __restrict__ PD0, float* __restrict__ ZS,
    double* __restrict__ acc) {
  const int kc = blockIdx.x * 256 + threadIdx.x;  // 0..1023
  const int k = kc * 2;
  const int chunk = blockIdx.y;
  const int i0 = chunk * L_;
  const int nrow = min(L_, N_ - i0);

  f2 p = 1.f, zl = 0.f;

  if (nrow == L_) {
    for (int sb = 0; sb < L_; sb += 4) {
      f2 lw[4], a[4], v[4], rr[4];
      float o[4];
#pragma unroll
      for (int j = 0; j < 4; ++j) {  // independent loads first (MLP)
        const int i = i0 + sb + j;
        const size_t b1 = (size_t)(i + 1) * K_ + k;
        const size_t b0 = (size_t)i * K_ + k;
        lw[j] = *(const f2*)(tlogp + b1);
        a[j] = *(const f2*)(tsv + b1);
        v[j] = *(const f2*)(tev + b1);
        rr[j] = *(const f2*)(r + b0);
        o[j] = ologp[i + 1];
      }
#pragma unroll
      for (int j = 0; j < 4; ++j) {  // serial cumprod chain
        f2 iw, td, y;
#pragma unroll
        for (int x = 0; x < 2; ++x) iw[x] = __expf(fminf(lw[j][x] - o[j], 0.f));
        p *= GAMMA * iw;
#pragma unroll
        for (int x = 0; x < 2; ++x)
          td[x] = fmaf(GAMMA, fmaf(-iw[x], a[j][x], v[j][x]), rr[j][x]);
        y = td * p;
        zl += y;
        if (STORE) {
          const size_t b0 = (size_t)(i0 + sb + j) * K_ + k;
          uu2 q;
#pragma unroll
          for (int x = 0; x < 2; ++x)
            q[x] = ((unsigned)f2bf(y[x]) << 16) | f2bf(p[x]);
          *(uu2*)(pk + b0) = q;
        }
      }
    }
  } else {
    for (int s = 0; s < nrow; ++s) {
      const int i = i0 + s;
      const size_t b1 = (size_t)(i + 1) * K_ + k;
      const size_t b0 = (size_t)i * K_ + k;
      f2 lw = *(const f2*)(tlogp + b1);
      f2 a = *(const f2*)(tsv + b1);
      f2 v = *(const f2*)(tev + b1);
      f2 rr = *(const f2*)(r + b0);
      const float o = ologp[i + 1];
      f2 iw, td, y;
#pragma unroll
      for (int x = 0; x < 2; ++x) iw[x] = __expf(fminf(lw[x] - o, 0.f));
      p *= GAMMA * iw;
#pragma unroll
      for (int x = 0; x < 2; ++x)
        td[x] = fmaf(GAMMA, fmaf(-iw[x], a[x], v[x]), rr[x]);
      y = td * p;
      zl += y;
      if (STORE) {
        uu2 q;
#pragma unroll
        for (int x = 0; x < 2; ++x)
          q[x] = ((unsigned)f2bf(y[x]) << 16) | f2bf(p[x]);
        *(uu2*)(pk + b0) = q;
      }
    }
  }
  *(f2*)(PD0 + (size_t)chunk * K_ + k) = p;
  *(f2*)(ZS + (size_t)chunk * K_ + k) = zl;
  if (blockIdx.x == 0 && blockIdx.y == 0 && threadIdx.x == 0) *acc = 0.0;
}

// ---------------------------------------------------------------- kS1
// Per (col, superchunk): SP = prod of 16 chunk-P; SZ = sum D0local*Zl.
__global__ __launch_bounds__(256) void kS1(const float* __restrict__ PD0,
                                           const float* __restrict__ ZS,
                                           float* __restrict__ SP,
                                           float* __restrict__ SZ) {
  const int g = blockIdx.x * 256 + threadIdx.x;  // 0..K*SUP-1
  const int k = g & (K_ - 1);
  const int s = g >> 11;  // /K_
  float sp = 1.f, sz = 0.f;
#pragma unroll
  for (int c = 0; c < SL; ++c) {
    const size_t idx = (size_t)(s * SL + c) * K_ + k;
    float pv = PD0[idx];
    float zv = ZS[idx];
    sz = fmaf(sp, zv, sz);
    sp *= pv;
  }
  SP[(size_t)s * K_ + k] = sp;
  SZ[(size_t)s * K_ + k] = sz;
}

// ---------------------------------------------------------------- kS2
// Per column: exclusive prefix product SD0 and suffix sum SSuf over sups.
__global__ __launch_bounds__(256) void kS2(const float* __restrict__ SP,
                                           const float* __restrict__ SZ,
                                           float* __restrict__ SD0,
                                           float* __restrict__ SSuf) {
  const int k = blockIdx.x * 256 + threadIdx.x;  // 0..K-1
  float d = 1.f;
  float sd[SUP];
#pragma unroll
  for (int s = 0; s < SUP; ++s) {
    sd[s] = d;
    SD0[(size_t)s * K_ + k] = d;
    d *= SP[(size_t)s * K_ + k];
  }
  float ss = 0.f;
#pragma unroll
  for (int s = SUP - 1; s >= 0; --s) {
    SSuf[(size_t)s * K_ + k] = ss;
    ss = fmaf(sd[s], SZ[(size_t)s * K_ + k], ss);
  }
}

// ---------------------------------------------------------------- kS3
// Expand to per-chunk D0 (in place over P) and Ssuf (in place over Zl).
// Same-thread read-then-write per element => no race.
__global__ __launch_bounds__(256) void kS3(float* __restrict__ PD0,
                                           float* __restrict__ ZS,
                                           const float* __restrict__ SD0,
                                           const float* __restrict__ SSuf) {
  const int g = blockIdx.x * 256 + threadIdx.x;
  const int k = g & (K_ - 1);
  const int s = g >> 11;
  float d = SD0[(size_t)s * K_ + k];
  float darr[SL];
#pragma unroll
  for (int c = 0; c < SL; ++c) {
    const size_t idx = (size_t)(s * SL + c) * K_ + k;
    float pv = PD0[idx];
    darr[c] = d;
    PD0[idx] = d;  // D0_c
    d *= pv;
  }
  float ss = SSuf[(size_t)s * K_ + k];
#pragma unroll
  for (int c = SL - 1; c >= 0; --c) {
    const size_t idx = (size_t)(s * SL + c) * K_ + k;
    float zv = ZS[idx];
    ZS[idx] = ss;  // Ssuf_c (excludes own chunk)
    ss = fmaf(darr[c], zv, ss);
  }
}

// ---------------------------------------------------------------- kB
__global__ __launch_bounds__(256) void kB(const float* __restrict__ sv,
                                          const unsigned* __restrict__ pk,
                                          const float* __restrict__ D0,
                                          const float* __restrict__ Ssuf,
                                          double* __restrict__ acc) {
  const int kc = blockIdx.x * 256 + threadIdx.x;
  const int k = kc * 2;
  const int chunk = blockIdx.y;
  const int i0 = chunk * L_;
  const int nrow = min(L_, N_ - i0);

  f2 d0 = *(const f2*)(D0 + (size_t)chunk * K_ + k);
  f2 ssuf = *(const f2*)(Ssuf + (size_t)chunk * K_ + k);
  f2 slocal = 0.f, loss = 0.f;

  auto compute = [&](uu2 q, f2 sv2) {
#pragma unroll
    for (int x = 0; x < 2; ++x) {
      float y = bfhi(q[x]);
      float ld = bflo(q[x]);
      slocal[x] += y;
      float S = fmaf(d0[x], slocal[x], ssuf[x]);
      float retrace = S / fmaxf(d0[x] * ld, 1e-10f);
      float dd = sv2[x] - retrace;
      float ad = fabsf(dd);
      loss[x] += (ad < 1.f) ? 0.5f * dd * dd : ad - 0.5f;
    }
  };

  if (nrow == L_) {
    for (int sb = L_ - 4; sb >= 0; sb -= 4) {
      uu2 q[4];
      f2 sv2[4];
#pragma unroll
      for (int j = 0; j < 4; ++j) {  // batch loads (MLP)
        const size_t b0 = (size_t)(i0 + sb + j) * K_ + k;
        q[j] = *(const uu2*)(pk + b0);
        sv2[j] = *(const f2*)(sv + b0);
      }
#pragma unroll
      for (int j = 3; j >= 0; --j) compute(q[j], sv2[j]);
    }
  } else {
    for (int s = nrow - 1; s >= 0; --s) {
      const size_t b0 = (size_t)(i0 + s) * K_ + k;
      compute(*(const uu2*)(pk + b0), *(const f2*)(sv + b0));
    }
  }

  float l = loss[0] + loss[1];
  for (int off = 32; off > 0; off >>= 1) l += __shfl_down(l, off);
  __shared__ float wsum[4];
  const int lane = threadIdx.x & 63, wid = threadIdx.x >> 6;
  if (lane == 0) wsum[wid] = l;
  __syncthreads();
  if (threadIdx.x == 0)
    atomicAdd(acc, (double)(wsum[0] + wsum[1] + wsum[2] + wsum[3]));
}

// ---------------------------------------------------------------- k3f
// Fallback apply (recomputes inputs) if ws can't hold the packed array.
__global__ __launch_bounds__(256) void k3f(
    const float* __restrict__ sv, const float* __restrict__ tsv,
    const float* __restrict__ tev, const float* __restrict__ r,
    const float* __restrict__ ologp, const float* __restrict__ tlogp,
    const float* __restrict__ D0, const float* __restrict__ Ssuf,
    double* __restrict__ acc) {
  const int k = blockIdx.x * 256 + threadIdx.x;
  const int chunk = blockIdx.y;
  const int i0 = chunk * L_;
  const int nrow = min(L_, N_ - i0);

  float ld[L_], td[L_];
  float p = 1.f;
#pragma unroll
  for (int s = 0; s < L_; ++s) {
    if (s < nrow) {
      const int i = i0 + s;
      const size_t base = (size_t)(i + 1) * K_ + k;
      float iw = __expf(fminf(tlogp[base] - ologp[i + 1], 0.f));
      p *= GAMMA * iw;
      ld[s] = p;
      td[s] =
          fmaf(GAMMA, fmaf(-iw, tsv[base], tev[base]), r[(size_t)i * K_ + k]);
    }
  }
  const float d0 = D0[(size_t)chunk * K_ + k];
  const float ssuf = Ssuf[(size_t)chunk * K_ + k];
  float slocal = 0.f, loss = 0.f;
#pragma unroll
  for (int s = L_ - 1; s >= 0; --s) {
    if (s < nrow) {
      const int i = i0 + s;
      slocal = fmaf(td[s], ld[s], slocal);
      float S = fmaf(d0, slocal, ssuf);
      float retrace = S / fmaxf(d0 * ld[s], 1e-10f);
      float dd = sv[(size_t)i * K_ + k] - retrace;
      float ad = fabsf(dd);
      loss += (ad < 1.f) ? 0.5f * dd * dd : ad - 0.5f;
    }
  }
  for (int off = 32; off > 0; off >>= 1) loss += __shfl_down(loss, off);
  __shared__ float wsum[4];
  const int lane = threadIdx.x & 63, wid = threadIdx.x >> 6;
  if (lane == 0) wsum[wid] = loss;
  __syncthreads();
  if (threadIdx.x == 0)
    atomicAdd(acc, (double)(wsum[0] + wsum[1] + wsum[2] + wsum[3]));
}

// ---------------------------------------------------------------- k4
__global__ void k4(const double* __restrict__ acc, float* __restrict__ out) {
  out[0] = (float)(*acc * (1.0 / ((double)N_ * (double)K_)));
}

extern "C" void kernel_launch(void* const* d_in, const int* in_sizes, int n_in,
                              void* d_out, int out_size, void* d_ws,
                              size_t ws_size, hipStream_t stream) {
  const float* sv = (const float*)d_in[0];
  const float* tsv = (const float*)d_in[1];
  const float* tev = (const float*)d_in[2];
  const float* r = (const float*)d_in[3];
  const float* ologp = (const float*)d_in[4];
  const float* tlogp = (const float*)d_in[5];

  const size_t pkBytes = (size_t)NK * 4;           // 67.1 MB packed y|ld
  const size_t ckBytes = (size_t)CK * 4;           // 2 MB each
  const size_t skBytes = (size_t)SUP * K_ * 4;     // 128 KB each
  const size_t needBig = pkBytes + 2 * ckBytes + 4 * skBytes + 8;
  const size_t needSmall = 2 * ckBytes + 4 * skBytes + 8;

  const dim3 gridA(K_ / 2 / 256, NCHUNK);  // (4,256): 4096 waves
  const int gridS = K_ * SUP / 256;        // 128 blocks

  if (ws_size >= needBig) {
    unsigned* pk = (unsigned*)d_ws;
    float* f = (float*)((char*)d_ws + pkBytes);
    float* PD0 = f;                // P, then D0 in place
    float* ZS = f + CK;            // Zl, then Ssuf in place
    float* SP = f + 2 * (size_t)CK;
    float* SZ = SP + (size_t)SUP * K_;
    float* SD0 = SZ + (size_t)SUP * K_;
    float* SSuf = SD0 + (size_t)SUP * K_;
    double* acc = (double*)(SSuf + (size_t)SUP * K_);

    kA<true><<<gridA, 256, 0, stream>>>(tsv, tev, r, ologp, tlogp, pk, PD0, ZS,
                                        acc);
    kS1<<<gridS, 256, 0, stream>>>(PD0, ZS, SP, SZ);
    kS2<<<K_ / 256, 256, 0, stream>>>(SP, SZ, SD0, SSuf);
    kS3<<<gridS, 256, 0, stream>>>(PD0, ZS, SD0, SSuf);
    kB<<<gridA, 256, 0, stream>>>(sv, pk, PD0, ZS, acc);
    k4<<<1, 1, 0, stream>>>(acc, (float*)d_out);
  } else if (ws_size >= needSmall) {
    float* f = (float*)d_ws;
    float* PD0 = f;
    float* ZS = f + CK;
    float* SP = f + 2 * (size_t)CK;
    float* SZ = SP + (size_t)SUP * K_;
    float* SD0 = SZ + (size_t)SUP * K_;
    float* SSuf = SD0 + (size_t)SUP * K_;
    double* acc = (double*)(SSuf + (size_t)SUP * K_);

    kA<false><<<gridA, 256, 0, stream>>>(tsv, tev, r, ologp, tlogp, nullptr,
                                         PD0, ZS, acc);
    kS1<<<gridS, 256, 0, stream>>>(PD0, ZS, SP, SZ);
    kS2<<<K_ / 256, 256, 0, stream>>>(SP, SZ, SD0, SSuf);
    kS3<<<gridS, 256, 0, stream>>>(PD0, ZS, SD0, SSuf);
    k3f<<<dim3(K_ / 256, NCHUNK), 256, 0, stream>>>(sv, tsv, tev, r, ologp,
                                                    tlogp, PD0, ZS, acc);
    k4<<<1, 1, 0, stream>>>(acc, (float*)d_out);
  }
}

// Round 4
// 106.882 us; speedup vs baseline: 1.6365x; 1.1050x over previous
//
#include <hip/hip_runtime.h>

// Retrace loss: T=8192, K=2048, gamma=0.99.
// decay = cumprod(gamma*iw); S = reverse-cumsum(td*decay);
// retrace = S / max(decay,1e-10); loss = mean(smooth_l1(q, retrace)).
//
// kA (fused tile): phase 1 streams inputs elementwise (float4, pipelined,
//   no dependency chain -> full MLP) into LDS tiles c(f32)/td(bf16);
//   phase 2 chains 32 rows per column from LDS, writes packed bf16 y|ld
//   plus per-chunk P, Zl.  Rounds 2-3 lesson: any serial chain adjacent to
//   the global loads makes hipcc drop to ~0.5 loads in flight (VGPR=28).
// kS1/kS2/kS3: hierarchical chunk scan (2 MB arrays, in-place D0/Ssuf).
// kB: backward within chunk from packed y/ld; fused smooth-L1 + reduce.

#define GAMMA 0.99f

constexpr int T_ = 8192;
constexpr int K_ = 2048;
constexpr int N_ = T_ - 1;        // 8191
constexpr int L_ = 32;            // rows per chunk
constexpr int NCHUNK = 256;      // last chunk: 31 rows
constexpr int SL = 16;            // chunks per superchunk
constexpr int SUP = NCHUNK / SL;  // 16
constexpr long long NK = (long long)N_ * K_;
constexpr int CK = NCHUNK * K_;

typedef float f4 __attribute__((ext_vector_type(4)));
typedef float f2 __attribute__((ext_vector_type(2)));
typedef unsigned short us4 __attribute__((ext_vector_type(4)));
typedef unsigned uu2 __attribute__((ext_vector_type(2)));

__device__ __forceinline__ unsigned short f2bf(float f) {  // RTNE
  unsigned u = __float_as_uint(f);
  u += 0x7FFFu + ((u >> 16) & 1u);
  return (unsigned short)(u >> 16);
}
__device__ __forceinline__ float bfhi(unsigned q) {  // y in hi16
  return __uint_as_float(q & 0xFFFF0000u);
}
__device__ __forceinline__ float bflo(unsigned q) {  // ld in lo16
  return __uint_as_float(q << 16);
}
__device__ __forceinline__ float bf2f(unsigned short h) {
  return __uint_as_float(((unsigned)h) << 16);
}

// ---------------------------------------------------------------- kA
// Tile: 32 rows x 256 cols. Grid (K/256, NCHUNK), 256 threads.
template <bool STORE>
__global__ __launch_bounds__(256, 3) void kA(
    const float* __restrict__ tsv, const float* __restrict__ tev,
    const float* __restrict__ r, const float* __restrict__ ologp,
    const float* __restrict__ tlogp, unsigned* __restrict__ pk,
    float* __restrict__ PD0, float* __restrict__ ZS,
    double* __restrict__ acc) {
  __shared__ float csh[L_][256];           // 32 KB, f32 c (exact chain)
  __shared__ unsigned short tdsh[L_][256];  // 16 KB, bf16 td
  const int tid = threadIdx.x;
  const int lane = tid & 63;
  const int wid = tid >> 6;
  const int c0 = blockIdx.x * 256;
  const int chunk = blockIdx.y;
  const int i0 = chunk * L_;
  const int col = c0 + lane * 4;

  // ---- phase 1: elementwise stream -> LDS. Wave w handles rows w,w+4,...
  f4 lwA, aA, vA, rrA;
  float oA;
  auto issue = [&](int s, f4& lw, f4& a, f4& v, f4& rr, float& o) {
    int i = i0 + s;
    if (i >= N_) i = N_ - 1;  // clamp; masked in phase 2
    const size_t b1 = (size_t)(i + 1) * K_ + col;
    const size_t b0 = (size_t)i * K_ + col;
    lw = *(const f4*)(tlogp + b1);
    a = *(const f4*)(tsv + b1);
    v = *(const f4*)(tev + b1);
    rr = *(const f4*)(r + b0);
    o = ologp[i + 1];
  };
  issue(wid, lwA, aA, vA, rrA, oA);
#pragma unroll
  for (int s0 = 0; s0 < L_; s0 += 4) {
    const int s = s0 + wid;
    f4 lwB, aB, vB, rrB;
    float oB;
    if (s0 + 4 < L_) issue(s + 4, lwB, aB, vB, rrB, oB);
    __builtin_amdgcn_sched_barrier(0);  // keep next batch's loads issued early
    f4 iw, c, td;
#pragma unroll
    for (int x = 0; x < 4; ++x) iw[x] = __expf(fminf(lwA[x] - oA, 0.f));
#pragma unroll
    for (int x = 0; x < 4; ++x) c[x] = GAMMA * iw[x];
#pragma unroll
    for (int x = 0; x < 4; ++x)
      td[x] = fmaf(GAMMA, fmaf(-iw[x], aA[x], vA[x]), rrA[x]);
    *(f4*)&csh[s][lane * 4] = c;
    us4 t4;
#pragma unroll
    for (int x = 0; x < 4; ++x) t4[x] = f2bf(td[x]);
    *(us4*)&tdsh[s][lane * 4] = t4;
    lwA = lwB;
    aA = aB;
    vA = vB;
    rrA = rrB;
    oA = oB;
  }
  __syncthreads();

  // ---- phase 2: per-column f32 chain over the tile (cheap VALU)
  const int kcol = c0 + tid;
  const int nrow = min(L_, N_ - i0);
  float p = 1.f, zl = 0.f;
#pragma unroll
  for (int s = 0; s < L_; ++s) {
    if (s < nrow) {
      float cc = csh[s][tid];
      float tdv = bf2f(tdsh[s][tid]);
      p *= cc;
      float y = tdv * p;
      zl += y;
      if (STORE) {
        pk[(size_t)(i0 + s) * K_ + kcol] =
            ((unsigned)f2bf(y) << 16) | f2bf(p);
      }
    }
  }
  PD0[(size_t)chunk * K_ + kcol] = p;
  ZS[(size_t)chunk * K_ + kcol] = zl;
  if (blockIdx.x == 0 && blockIdx.y == 0 && tid == 0) *acc = 0.0;
}

// ---------------------------------------------------------------- kS1
// Per (col, superchunk): SP = prod of 16 chunk-P; SZ = sum D0local*Zl.
__global__ __launch_bounds__(256) void kS1(const float* __restrict__ PD0,
                                           const float* __restrict__ ZS,
                                           float* __restrict__ SP,
                                           float* __restrict__ SZ) {
  const int g = blockIdx.x * 256 + threadIdx.x;  // 0..K*SUP-1
  const int k = g & (K_ - 1);
  const int s = g >> 11;  // /K_
  float sp = 1.f, sz = 0.f;
#pragma unroll
  for (int c = 0; c < SL; ++c) {
    const size_t idx = (size_t)(s * SL + c) * K_ + k;
    float pv = PD0[idx];
    float zv = ZS[idx];
    sz = fmaf(sp, zv, sz);
    sp *= pv;
  }
  SP[(size_t)s * K_ + k] = sp;
  SZ[(size_t)s * K_ + k] = sz;
}

// ---------------------------------------------------------------- kS2
// Per column: exclusive prefix product SD0 and suffix sum SSuf over sups.
__global__ __launch_bounds__(256) void kS2(const float* __restrict__ SP,
                                           const float* __restrict__ SZ,
                                           float* __restrict__ SD0,
                                           float* __restrict__ SSuf) {
  const int k = blockIdx.x * 256 + threadIdx.x;  // 0..K-1
  float d = 1.f;
  float sd[SUP];
#pragma unroll
  for (int s = 0; s < SUP; ++s) {
    sd[s] = d;
    SD0[(size_t)s * K_ + k] = d;
    d *= SP[(size_t)s * K_ + k];
  }
  float ss = 0.f;
#pragma unroll
  for (int s = SUP - 1; s >= 0; --s) {
    SSuf[(size_t)s * K_ + k] = ss;
    ss = fmaf(sd[s], SZ[(size_t)s * K_ + k], ss);
  }
}

// ---------------------------------------------------------------- kS3
// Expand to per-chunk D0 (in place over P) and Ssuf (in place over Zl).
// Same-thread read-then-write per element => no race.
__global__ __launch_bounds__(256) void kS3(float* __restrict__ PD0,
                                           float* __restrict__ ZS,
                                           const float* __restrict__ SD0,
                                           const float* __restrict__ SSuf) {
  const int g = blockIdx.x * 256 + threadIdx.x;
  const int k = g & (K_ - 1);
  const int s = g >> 11;
  float d = SD0[(size_t)s * K_ + k];
  float darr[SL];
#pragma unroll
  for (int c = 0; c < SL; ++c) {
    const size_t idx = (size_t)(s * SL + c) * K_ + k;
    float pv = PD0[idx];
    darr[c] = d;
    PD0[idx] = d;  // D0_c
    d *= pv;
  }
  float ss = SSuf[(size_t)s * K_ + k];
#pragma unroll
  for (int c = SL - 1; c >= 0; --c) {
    const size_t idx = (size_t)(s * SL + c) * K_ + k;
    float zv = ZS[idx];
    ZS[idx] = ss;  // Ssuf_c (excludes own chunk)
    ss = fmaf(darr[c], zv, ss);
  }
}

// ---------------------------------------------------------------- kB
__global__ __launch_bounds__(256) void kB(const float* __restrict__ sv,
                                          const unsigned* __restrict__ pk,
                                          const float* __restrict__ D0,
                                          const float* __restrict__ Ssuf,
                                          double* __restrict__ acc) {
  const int kc = blockIdx.x * 256 + threadIdx.x;
  const int k = kc * 2;
  const int chunk = blockIdx.y;
  const int i0 = chunk * L_;
  const int nrow = min(L_, N_ - i0);

  f2 d0 = *(const f2*)(D0 + (size_t)chunk * K_ + k);
  f2 ssuf = *(const f2*)(Ssuf + (size_t)chunk * K_ + k);
  f2 slocal = 0.f, loss = 0.f;

  auto compute = [&](uu2 q, f2 sv2) {
#pragma unroll
    for (int x = 0; x < 2; ++x) {
      float y = bfhi(q[x]);
      float ld = bflo(q[x]);
      slocal[x] += y;
      float S = fmaf(d0[x], slocal[x], ssuf[x]);
      float retrace = S / fmaxf(d0[x] * ld, 1e-10f);
      float dd = sv2[x] - retrace;
      float ad = fabsf(dd);
      loss[x] += (ad < 1.f) ? 0.5f * dd * dd : ad - 0.5f;
    }
  };

  if (nrow == L_) {
    for (int sb = L_ - 4; sb >= 0; sb -= 4) {
      uu2 q[4];
      f2 sv2[4];
#pragma unroll
      for (int j = 0; j < 4; ++j) {  // batch loads (MLP)
        const size_t b0 = (size_t)(i0 + sb + j) * K_ + k;
        q[j] = *(const uu2*)(pk + b0);
        sv2[j] = *(const f2*)(sv + b0);
      }
#pragma unroll
      for (int j = 3; j >= 0; --j) compute(q[j], sv2[j]);
    }
  } else {
    for (int s = nrow - 1; s >= 0; --s) {
      const size_t b0 = (size_t)(i0 + s) * K_ + k;
      compute(*(const uu2*)(pk + b0), *(const f2*)(sv + b0));
    }
  }

  float l = loss[0] + loss[1];
  for (int off = 32; off > 0; off >>= 1) l += __shfl_down(l, off);
  __shared__ float wsum[4];
  const int lane = threadIdx.x & 63, wid = threadIdx.x >> 6;
  if (lane == 0) wsum[wid] = l;
  __syncthreads();
  if (threadIdx.x == 0)
    atomicAdd(acc, (double)(wsum[0] + wsum[1] + wsum[2] + wsum[3]));
}

// ---------------------------------------------------------------- k3f
// Fallback apply (recomputes inputs) if ws can't hold the packed array.
__global__ __launch_bounds__(256) void k3f(
    const float* __restrict__ sv, const float* __restrict__ tsv,
    const float* __restrict__ tev, const float* __restrict__ r,
    const float* __restrict__ ologp, const float* __restrict__ tlogp,
    const float* __restrict__ D0, const float* __restrict__ Ssuf,
    double* __restrict__ acc) {
  const int k = blockIdx.x * 256 + threadIdx.x;
  const int chunk = blockIdx.y;
  const int i0 = chunk * L_;
  const int nrow = min(L_, N_ - i0);

  float ld[L_], td[L_];
  float p = 1.f;
#pragma unroll
  for (int s = 0; s < L_; ++s) {
    if (s < nrow) {
      const int i = i0 + s;
      const size_t base = (size_t)(i + 1) * K_ + k;
      float iw = __expf(fminf(tlogp[base] - ologp[i + 1], 0.f));
      p *= GAMMA * iw;
      ld[s] = p;
      td[s] =
          fmaf(GAMMA, fmaf(-iw, tsv[base], tev[base]), r[(size_t)i * K_ + k]);
    }
  }
  const float d0 = D0[(size_t)chunk * K_ + k];
  const float ssuf = Ssuf[(size_t)chunk * K_ + k];
  float slocal = 0.f, loss = 0.f;
#pragma unroll
  for (int s = L_ - 1; s >= 0; --s) {
    if (s < nrow) {
      const int i = i0 + s;
      slocal = fmaf(td[s], ld[s], slocal);
      float S = fmaf(d0, slocal, ssuf);
      float retrace = S / fmaxf(d0 * ld[s], 1e-10f);
      float dd = sv[(size_t)i * K_ + k] - retrace;
      float ad = fabsf(dd);
      loss += (ad < 1.f) ? 0.5f * dd * dd : ad - 0.5f;
    }
  }
  for (int off = 32; off > 0; off >>= 1) loss += __shfl_down(loss, off);
  __shared__ float wsum[4];
  const int lane = threadIdx.x & 63, wid = threadIdx.x >> 6;
  if (lane == 0) wsum[wid] = loss;
  __syncthreads();
  if (threadIdx.x == 0)
    atomicAdd(acc, (double)(wsum[0] + wsum[1] + wsum[2] + wsum[3]));
}

// ---------------------------------------------------------------- k4
__global__ void k4(const double* __restrict__ acc, float* __restrict__ out) {
  out[0] = (float)(*acc * (1.0 / ((double)N_ * (double)K_)));
}

extern "C" void kernel_launch(void* const* d_in, const int* in_sizes, int n_in,
                              void* d_out, int out_size, void* d_ws,
                              size_t ws_size, hipStream_t stream) {
  const float* sv = (const float*)d_in[0];
  const float* tsv = (const float*)d_in[1];
  const float* tev = (const float*)d_in[2];
  const float* r = (const float*)d_in[3];
  const float* ologp = (const float*)d_in[4];
  const float* tlogp = (const float*)d_in[5];

  const size_t pkBytes = (size_t)NK * 4;        // 67.1 MB packed y|ld
  const size_t ckBytes = (size_t)CK * 4;        // 2 MB each
  const size_t skBytes = (size_t)SUP * K_ * 4;  // 128 KB each
  const size_t needBig = pkBytes + 2 * ckBytes + 4 * skBytes + 8;
  const size_t needSmall = 2 * ckBytes + 4 * skBytes + 8;

  const dim3 gridT(K_ / 256, NCHUNK);      // (8,256) tile kernel
  const dim3 gridB(K_ / 2 / 256, NCHUNK);  // (4,256) kB float2
  const int gridS = K_ * SUP / 256;        // 128 blocks

  if (ws_size >= needBig) {
    unsigned* pk = (unsigned*)d_ws;
    float* f = (float*)((char*)d_ws + pkBytes);
    float* PD0 = f;      // P, then D0 in place
    float* ZS = f + CK;  // Zl, then Ssuf in place
    float* SP = f + 2 * (size_t)CK;
    float* SZ = SP + (size_t)SUP * K_;
    float* SD0 = SZ + (size_t)SUP * K_;
    float* SSuf = SD0 + (size_t)SUP * K_;
    double* acc = (double*)(SSuf + (size_t)SUP * K_);

    kA<true><<<gridT, 256, 0, stream>>>(tsv, tev, r, ologp, tlogp, pk, PD0, ZS,
                                        acc);
    kS1<<<gridS, 256, 0, stream>>>(PD0, ZS, SP, SZ);
    kS2<<<K_ / 256, 256, 0, stream>>>(SP, SZ, SD0, SSuf);
    kS3<<<gridS, 256, 0, stream>>>(PD0, ZS, SD0, SSuf);
    kB<<<gridB, 256, 0, stream>>>(sv, pk, PD0, ZS, acc);
    k4<<<1, 1, 0, stream>>>(acc, (float*)d_out);
  } else if (ws_size >= needSmall) {
    float* f = (float*)d_ws;
    float* PD0 = f;
    float* ZS = f + CK;
    float* SP = f + 2 * (size_t)CK;
    float* SZ = SP + (size_t)SUP * K_;
    float* SD0 = SZ + (size_t)SUP * K_;
    float* SSuf = SD0 + (size_t)SUP * K_;
    double* acc = (double*)(SSuf + (size_t)SUP * K_);

    kA<false><<<gridT, 256, 0, stream>>>(tsv, tev, r, ologp, tlogp, nullptr,
                                         PD0, ZS, acc);
    kS1<<<gridS, 256, 0, stream>>>(PD0, ZS, SP, SZ);
    kS2<<<K_ / 256, 256, 0, stream>>>(SP, SZ, SD0, SSuf);
    kS3<<<gridS, 256, 0, stream>>>(PD0, ZS, SD0, SSuf);
    k3f<<<dim3(K_ / 256, NCHUNK), 256, 0, stream>>>(sv, tsv, tev, r, ologp,
                                                    tlogp, PD0, ZS, acc);
    k4<<<1, 1, 0, stream>>>(acc, (float*)d_out);
  }
}